// Round 3
// baseline (72.829 us; speedup 1.0000x reference)
//
#include <hip/hip_runtime.h>

#define NK 19
#define NB 8
#define NC 256
#define NP 8192           // 64*128
#define NBP (NB*NP)       // 65536

typedef unsigned char u8;

// ---------------- kernel 1: argmax over classes + integer counts ----------------
__global__ __launch_bounds__(256) void k_argmax(const float* __restrict__ target,
                                                u8* __restrict__ lab,
                                                int* __restrict__ counts) {
  __shared__ float tl[256 * NK];                 // 19456 B
  __shared__ int lcnt[NK];
  if (threadIdx.x < NK) lcnt[threadIdx.x] = 0;
  const float4* src = (const float4*)(target + (size_t)blockIdx.x * (256 * NK));
  float4* dst = (float4*)tl;
  for (int i = threadIdx.x; i < 256 * NK / 4; i += 256) dst[i] = src[i];
  __syncthreads();
  const float* row = &tl[threadIdx.x * NK];
  float best = row[0]; int bk = 0;
#pragma unroll
  for (int k = 1; k < NK; ++k) { float v = row[k]; if (v > best) { best = v; bk = k; } }
  int g = blockIdx.x * 256 + threadIdx.x;
  lab[g] = (u8)bk;
  atomicAdd(&lcnt[bk], 1);
  __syncthreads();
  int b = g >> 13;                               // / NP (block is within one b)
  if (threadIdx.x < NK) atomicAdd(&counts[b * NK + threadIdx.x], lcnt[threadIdx.x]);
}

// ---------------- kernel 2: per-(feat,b,c) class sums, bin-major conflict-free hist ----------------
__global__ __launch_bounds__(256) void k_sums(const float* __restrict__ fS,
                                              const float* __restrict__ fT,
                                              const u8* __restrict__ lab,
                                              float* __restrict__ sums) {
  __shared__ float bins[NK * 256];               // 19456 B; bank = t%32, label-independent
  int id = blockIdx.x;                           // [0, 2*NB*NC)
  int f = id >> 11;
  int b = (id >> 8) & 7;
  int c = id & 255;
  int t = threadIdx.x;
  // zero (stride-1 float4, conflict-free)
  float4* bz = (float4*)bins;
  for (int i = t; i < NK * 64; i += 256) bz[i] = make_float4(0.f, 0.f, 0.f, 0.f);
  __syncthreads();
  const float4* rv = (const float4*)((f ? fT : fS) + ((size_t)(b * NC + c)) * NP);
  const uchar4* lb = (const uchar4*)(lab + b * NP);
#pragma unroll
  for (int i = 0; i < 8; ++i) {
    int p4 = i * 256 + t;
    float4 v = rv[p4];
    uchar4 l = lb[p4];
    bins[l.x * 256 + t] += v.x;                  // bank = t%32 for all four: zero conflicts
    bins[l.y * 256 + t] += v.y;
    bins[l.z * 256 + t] += v.z;
    bins[l.w * 256 + t] += v.w;
  }
  __syncthreads();
  // reduce: wave w handles bins w, w+4, ... ; one ds_read_b128 row read + shuffle tree
  int wave = t >> 6, lane = t & 63;
  for (int k = wave; k < NK; k += 4) {
    float4 v = *(const float4*)&bins[k * 256 + lane * 4];
#pragma unroll
    for (int off = 32; off > 0; off >>= 1) {
      v.x += __shfl_down(v.x, off);
      v.y += __shfl_down(v.y, off);
      v.z += __shfl_down(v.z, off);
      v.w += __shfl_down(v.w, off);
    }
    if (lane == 0) sums[(size_t)id * NK + k] = v.x + v.y + v.z + v.w;
  }
}

// ---------------- kernel 3: means + per-(f,b,k) center norms ----------------
__global__ __launch_bounds__(256) void k_means(const float* __restrict__ sums,
                                               const int* __restrict__ counts,
                                               float* __restrict__ means,
                                               float* __restrict__ cnorm) {
  int b = blockIdx.x / NK, k = blockIdx.x % NK;
  int c = threadIdx.x;
  float cnt = (float)counts[b * NK + k] + 1e-6f;
  size_t iS = ((size_t)(b * NC + c)) * NK + k;
  size_t iT = ((size_t)((NB + b) * NC + c)) * NK + k;
  float mS = sums[iS] / cnt;
  float mT = sums[iT] / cnt;
  means[iS] = mS;
  means[iT] = mT;
  float sS = mS * mS, sT = mT * mT;
#pragma unroll
  for (int off = 32; off > 0; off >>= 1) { sS += __shfl_down(sS, off, 64); sT += __shfl_down(sT, off, 64); }
  __shared__ float redS[4], redT[4];
  int wid = threadIdx.x >> 6, lane = threadIdx.x & 63;
  if (lane == 0) { redS[wid] = sS; redT[wid] = sT; }
  __syncthreads();
  if (threadIdx.x == 0) {
    float tS = redS[0] + redS[1] + redS[2] + redS[3];
    float tT = redT[0] + redT[1] + redT[2] + redT[3];
    cnorm[b * NK + k]           = fmaxf(sqrtf(tS), 1e-8f);
    cnorm[NB * NK + b * NK + k] = fmaxf(sqrtf(tT), 1e-8f);
  }
}

// ---------------- kernel 4: per-pixel cosine + squared diff (4-way channel split) ----------------
__global__ __launch_bounds__(256) void k_cos(const float* __restrict__ fS,
                                             const float* __restrict__ fT,
                                             const u8* __restrict__ lab,
                                             const float* __restrict__ means,
                                             const float* __restrict__ cnorm,
                                             float* __restrict__ partial) {
  __shared__ float R[1024];                      // 4 KB
  int b = blockIdx.x >> 7, pt = blockIdx.x & 127;
  int t = threadIdx.x;
  int px = t & 63, cg = t >> 6;                  // 4 channel-groups x 64 pixels
  int p = pt * 64 + px;
  int k = lab[b * NP + p];
  const float* rs = fS + (size_t)b * NC * NP + p;
  const float* rt = fT + (size_t)b * NC * NP + p;
  const float* mSb = means + (size_t)(b * NC) * NK;
  const float* mTb = means + (size_t)((NB + b) * NC) * NK;
  float dS = 0.f, nS = 0.f, dT = 0.f, nT = 0.f;
  int c0 = cg * 64;
#pragma unroll 8
  for (int j = 0; j < 64; ++j) {
    int c = c0 + j;
    float vS = rs[(size_t)c * NP];
    float vT = rt[(size_t)c * NP];
    float cS = mSb[c * NK + k];
    float cT = mTb[c * NK + k];
    dS += vS * cS; nS += vS * vS;
    dT += vT * cT; nT += vT * vT;
  }
  R[t] = dS; R[256 + t] = nS; R[512 + t] = dT; R[768 + t] = nT;
  __syncthreads();
  if (t < 64) {
    dS = R[t]       + R[64 + t]  + R[128 + t] + R[192 + t];
    nS = R[256 + t] + R[320 + t] + R[384 + t] + R[448 + t];
    dT = R[512 + t] + R[576 + t] + R[640 + t] + R[704 + t];
    nT = R[768 + t] + R[832 + t] + R[896 + t] + R[960 + t];
    float cnS = cnorm[b * NK + k];
    float cnT = cnorm[NB * NK + b * NK + k];
    float cosS = dS / (fmaxf(sqrtf(nS), 1e-8f) * cnS);
    float cosT = dT / (fmaxf(sqrtf(nT), 1e-8f) * cnT);
    float d = cosS - cosT;
    float v = d * d;
#pragma unroll
    for (int off = 32; off > 0; off >>= 1) v += __shfl_down(v, off, 64);
    if (px == 0) partial[blockIdx.x] = v;
  }
}

// ---------------- kernel 5: final deterministic reduction (1024 partials) ----------------
__global__ __launch_bounds__(256) void k_final(const float* __restrict__ partial,
                                               float* __restrict__ out) {
  int t = threadIdx.x;
  float v = partial[t] + partial[256 + t] + partial[512 + t] + partial[768 + t];
#pragma unroll
  for (int off = 32; off > 0; off >>= 1) v += __shfl_down(v, off, 64);
  __shared__ float red[4];
  int wid = t >> 6, lane = t & 63;
  if (lane == 0) red[wid] = v;
  __syncthreads();
  if (t == 0) out[0] = (red[0] + red[1] + red[2] + red[3]) * (1.0f / (float)NBP);
}

// ---------------- launch ----------------
extern "C" void kernel_launch(void* const* d_in, const int* in_sizes, int n_in,
                              void* d_out, int out_size, void* d_ws, size_t ws_size,
                              hipStream_t stream) {
  const float* fS     = (const float*)d_in[0];
  const float* fT     = (const float*)d_in[1];
  const float* target = (const float*)d_in[2];
  char* ws = (char*)d_ws;
  u8*    lab     = (u8*)   (ws + 0);        // 65536 B
  int*   counts  = (int*)  (ws + 65536);    // 608 B (pad to 66560)
  float* sums    = (float*)(ws + 66560);    // 311296 B -> 377856
  float* means   = (float*)(ws + 377856);   // 311296 B -> 689152
  float* cnorm   = (float*)(ws + 689152);   // 1216 B (pad to 690432)
  float* partial = (float*)(ws + 690432);   // 4096 B
  float* out = (float*)d_out;

  hipMemsetAsync(counts, 0, NB * NK * sizeof(int), stream);
  k_argmax<<<NBP / 256,   256, 0, stream>>>(target, lab, counts);
  k_sums  <<<2 * NB * NC, 256, 0, stream>>>(fS, fT, lab, sums);
  k_means <<<NB * NK,     256, 0, stream>>>(sums, counts, means, cnorm);
  k_cos   <<<NB * (NP / 64), 256, 0, stream>>>(fS, fT, lab, means, cnorm, partial);
  k_final <<<1, 256, 0, stream>>>(partial, out);
}